// Round 12
// baseline (210.013 us; speedup 1.0000x reference)
//
#include <hip/hip_runtime.h>
#include <hip/hip_fp16.h>
#include <math.h>

// GCN forward: h1 = relu(norm_agg(x@W1)+b1); h2 = norm_agg(h1@W2)+b2;
// g = mean_pool(h2, batch); out = g@Wl + bl.
// norm_agg = D^-1/2 (A+I) D^-1/2, CSR-by-dst pull.
// R3/R10: producer GEMM writes PRESCALED fp16 t = (in@W)*dinv (direct-frag
//   MFMA, W pre-transposed fp16, no LDS). R4: bucketed-counting-sort CSR.
// R8: 8-deep fp16 row gather. R9: agg2 -> pooled sums via f32 atomics.
// R12: R11 post-mortem isolated the regression to per-edge dinv[s] gathers
//   (NOT the MFMA tail, MfmaUtil was 4%). This round: R10 base (prescaled t1,
//   separate csr/gemm1) + ONLY the clean fusion: gemm2's 16-MFMA tail inside
//   agg1 (h1 row -> wave-local LDS -> MFMA vs L1-resident Wt2 -> t2).
//   h1 buffer + gemm2 dispatch eliminated; 8 -> 7 dispatches.

#define FEAT1 128
#define FEAT2 64
#define BCAP 8192   // edge capacity per bucket; avg load = 4096

using half8 = __attribute__((ext_vector_type(8))) _Float16;
using f32x4 = __attribute__((ext_vector_type(4))) float;

// ---------------- prep: zero bcur+pooled, transpose W1/W2 to fp16 ----------------
__global__ __launch_bounds__(256) void prep(const float* __restrict__ W1,
                                            const float* __restrict__ W2,
                                            _Float16* __restrict__ Wt1,
                                            _Float16* __restrict__ Wt2,
                                            int* __restrict__ bcur,
                                            float* __restrict__ pooled,
                                            int nb, int npool) {
    const int i = blockIdx.x * 256 + threadIdx.x;
    if (i < nb) bcur[i] = 0;
    const int j = i - nb;
    if (j >= 0 && j < npool) pooled[j] = 0.0f;
    if (i < 128 * 128) {                       // Wt1[c][k] = W1[k][c]
        int k = i & 127, c = i >> 7;
        Wt1[c * 128 + k] = (_Float16)W1[k * 128 + c];
    }
    if (i < 64 * 128) {                        // Wt2[c][k] = W2[k][c]
        int k = i & 127, c = i >> 7;
        Wt2[c * 128 + k] = (_Float16)W2[k * 64 + c];
    }
}

// ---------------- CSR pass 1: bucket scatter (8192 edges/block) ----------------
__global__ __launch_bounds__(256) void bin_scatter(const int* __restrict__ esrc,
                                                   const int* __restrict__ edst,
                                                   int ne, int nb,
                                                   int* __restrict__ bucket_cursor,
                                                   int* __restrict__ ebin) {
    __shared__ int lcnt[256];
    __shared__ int lcur[256];
    const int tid = threadIdx.x;
    const int e0 = blockIdx.x * 8192;
    int dcache[32];                     // edst cached in regs across phases
    lcnt[tid] = 0;
    __syncthreads();
    #pragma unroll
    for (int k = 0; k < 32; k++) {
        int e = e0 + k * 256 + tid;
        dcache[k] = (e < ne) ? edst[e] : -1;
        if (dcache[k] >= 0) atomicAdd(&lcnt[dcache[k] >> 8], 1);
    }
    __syncthreads();
    if (tid < nb && lcnt[tid] > 0)
        lcur[tid] = atomicAdd(&bucket_cursor[tid], lcnt[tid]);
    __syncthreads();
    #pragma unroll
    for (int k = 0; k < 32; k++) {
        int d = dcache[k];
        if (d >= 0) {
            int e = e0 + k * 256 + tid;
            int b = d >> 8;
            int p = atomicAdd(&lcur[b], 1);          // relative position
            if (p < BCAP)                            // capacity guard
                ebin[b * BCAP + p] = esrc[e] | ((d & 255) << 18); // src < 2^17
        }
    }
}

// ---------------- CSR pass 2: one block per bucket ----------------
__global__ __launch_bounds__(256) void bucket_csr(const int* __restrict__ ebin,
                                                  const int* __restrict__ bucket_cursor,
                                                  int n_nodes,
                                                  int* __restrict__ csr,
                                                  int2* __restrict__ nodeinfo,
                                                  float* __restrict__ dinv) {
    __shared__ int lcnt[256];
    __shared__ int lscan[256];
    __shared__ int lcur[256];
    const int b = blockIdx.x;
    const int tid = threadIdx.x;
    const int ebeg = b * BCAP;
    int cnt_b = bucket_cursor[b];
    if (cnt_b > BCAP) cnt_b = BCAP;
    const int eend = ebeg + cnt_b;
    lcnt[tid] = 0;
    __syncthreads();
    for (int e = ebeg + tid; e < eend; e += 256)
        atomicAdd(&lcnt[(ebin[e] >> 18) & 255], 1);
    __syncthreads();
    int v = lcnt[tid];
    lscan[tid] = v;
    __syncthreads();
    for (int off = 1; off < 256; off <<= 1) {
        int u = (tid >= off) ? lscan[tid - off] : 0;
        __syncthreads();
        lscan[tid] += u;
        __syncthreads();
    }
    const int start = ebeg + (lscan[tid] - v);   // exclusive scan position
    const int node = (b << 8) + tid;
    if (node < n_nodes) {
        nodeinfo[node] = make_int2(start, v);
        dinv[node] = (float)(1.0 / sqrt((double)(v + 1)));  // +1 self loop
    }
    lcur[tid] = start;
    __syncthreads();
    for (int e = ebeg + tid; e < eend; e += 256) {
        int pk = ebin[e];
        int p = atomicAdd(&lcur[(pk >> 18) & 255], 1);
        csr[p] = pk & 0x3FFFF;
    }
}

// ---------------- LDS-free direct-fragment MFMA GEMM (layer 1) ----------------
// t1[row, c] = fp16( (x[row,:128] @ W1[:128,c]) * dinv[row] )
__global__ __launch_bounds__(256) void gemm_direct(const float* __restrict__ A,
                                                   const _Float16* __restrict__ Wt,
                                                   const float* __restrict__ dinv,
                                                   _Float16* __restrict__ out, int n) {
    const int wv = threadIdx.x >> 6;
    const int lane = threadIdx.x & 63;
    const int row0 = blockIdx.x * 128 + wv * 32;   // this wave's 32 rows
    const int r16 = lane & 15;
    const int kb = (lane >> 4) * 8;                // k-offset within 32-k step

    half8 afrag[2][4];
    #pragma unroll
    for (int mi = 0; mi < 2; mi++) {
        const int grow = row0 + mi * 16 + r16;
        #pragma unroll
        for (int ks = 0; ks < 4; ks++) {
            float4 v0 = {0.f, 0.f, 0.f, 0.f}, v1 = {0.f, 0.f, 0.f, 0.f};
            if (grow < n) {
                const float* p = A + (size_t)grow * 128 + ks * 32 + kb;
                v0 = *(const float4*)(p);
                v1 = *(const float4*)(p + 4);
            }
            afrag[mi][ks] = half8{(_Float16)v0.x, (_Float16)v0.y, (_Float16)v0.z, (_Float16)v0.w,
                                  (_Float16)v1.x, (_Float16)v1.y, (_Float16)v1.z, (_Float16)v1.w};
        }
    }

    #pragma unroll
    for (int ct = 0; ct < 2; ct++) {
        const int col0 = ct * 64;
        f32x4 acc[2][4] = {};
        #pragma unroll
        for (int ks = 0; ks < 4; ks++) {
            #pragma unroll
            for (int nj = 0; nj < 4; nj++) {
                half8 b = *(const half8*)(Wt + (size_t)(col0 + nj * 16 + r16) * 128 + ks * 32 + kb);
                acc[0][nj] = __builtin_amdgcn_mfma_f32_16x16x32_f16(afrag[0][ks], b, acc[0][nj], 0, 0, 0);
                acc[1][nj] = __builtin_amdgcn_mfma_f32_16x16x32_f16(afrag[1][ks], b, acc[1][nj], 0, 0, 0);
            }
        }
        // C/D layout: col = lane&15, row = (lane>>4)*4 + reg
        #pragma unroll
        for (int mi = 0; mi < 2; mi++) {
            const int gr0 = row0 + mi * 16 + (lane >> 4) * 4;
            #pragma unroll
            for (int r = 0; r < 4; r++) {
                const int grow = gr0 + r;
                if (grow < n) {
                    const float s = dinv[grow];
                    #pragma unroll
                    for (int nj = 0; nj < 4; nj++)
                        out[(size_t)grow * 128 + col0 + nj * 16 + r16] =
                            (_Float16)(acc[mi][nj][r] * s);
                }
            }
        }
    }
}

// ---------------- fused agg1 (prescaled gather, R10 body) + gemm2 tail ----------------
// h1 = relu((sum_{s in N(i) u {i}} t1[s]) * dinv[i] + b1)   [t1 prescaled]
// t2[i][c] = fp16( (h1 @ W2[:,c]) * dinv[i] )  via wave-LDS + 16 MFMAs
__global__ __launch_bounds__(256) void agg1_gemm2(const __half* __restrict__ t,
                                                  const float* __restrict__ dinv,
                                                  const int2* __restrict__ nodeinfo,
                                                  const int* __restrict__ csr_src,
                                                  const float* __restrict__ bias,
                                                  const _Float16* __restrict__ Wt2,
                                                  _Float16* __restrict__ t2, int n) {
    constexpr int F = 128;
    __shared__ _Float16 hlds[4][128];
    const int wv = threadIdx.x >> 6;
    const int lane = threadIdx.x & 63;
    const int i = blockIdx.x * 4 + wv;
    if (i >= n) return;
    const float di = dinv[i];
    const int2 ni = nodeinfo[i];
    const int e0 = ni.x, e1 = ni.x + ni.y;

    float2 a0, a1 = {0.f, 0.f}, a2 = {0.f, 0.f}, a3 = {0.f, 0.f};
    a0 = __half22float2(((const __half2*)(t + (size_t)i * F))[lane]);  // self
    int e = e0;
    for (; e + 8 <= e1; e += 8) {     // 8 row-gathers in flight, pure adds
        int s0 = csr_src[e + 0], s1 = csr_src[e + 1], s2 = csr_src[e + 2], s3 = csr_src[e + 3];
        int s4 = csr_src[e + 4], s5 = csr_src[e + 5], s6 = csr_src[e + 6], s7 = csr_src[e + 7];
        float2 v0 = __half22float2(((const __half2*)(t + (size_t)s0 * F))[lane]);
        float2 v1 = __half22float2(((const __half2*)(t + (size_t)s1 * F))[lane]);
        float2 v2 = __half22float2(((const __half2*)(t + (size_t)s2 * F))[lane]);
        float2 v3 = __half22float2(((const __half2*)(t + (size_t)s3 * F))[lane]);
        float2 v4 = __half22float2(((const __half2*)(t + (size_t)s4 * F))[lane]);
        float2 v5 = __half22float2(((const __half2*)(t + (size_t)s5 * F))[lane]);
        float2 v6 = __half22float2(((const __half2*)(t + (size_t)s6 * F))[lane]);
        float2 v7 = __half22float2(((const __half2*)(t + (size_t)s7 * F))[lane]);
        a0.x += v0.x + v4.x; a0.y += v0.y + v4.y;
        a1.x += v1.x + v5.x; a1.y += v1.y + v5.y;
        a2.x += v2.x + v6.x; a2.y += v2.y + v6.y;
        a3.x += v3.x + v7.x; a3.y += v3.y + v7.y;
    }
    for (; e + 4 <= e1; e += 4) {
        int s0 = csr_src[e + 0], s1 = csr_src[e + 1], s2 = csr_src[e + 2], s3 = csr_src[e + 3];
        float2 v0 = __half22float2(((const __half2*)(t + (size_t)s0 * F))[lane]);
        float2 v1 = __half22float2(((const __half2*)(t + (size_t)s1 * F))[lane]);
        float2 v2 = __half22float2(((const __half2*)(t + (size_t)s2 * F))[lane]);
        float2 v3 = __half22float2(((const __half2*)(t + (size_t)s3 * F))[lane]);
        a0.x += v0.x; a0.y += v0.y;
        a1.x += v1.x; a1.y += v1.y;
        a2.x += v2.x; a2.y += v2.y;
        a3.x += v3.x; a3.y += v3.y;
    }
    for (; e < e1; e++) {
        int s = csr_src[e];
        float2 v = __half22float2(((const __half2*)(t + (size_t)s * F))[lane]);
        a0.x += v.x; a0.y += v.y;
    }
    float2 b = ((const float2*)bias)[lane];
    float rx = (a0.x + a1.x + a2.x + a3.x) * di + b.x;
    float ry = (a0.y + a1.y + a2.y + a3.y) * di + b.y;
    rx = fmaxf(rx, 0.f); ry = fmaxf(ry, 0.f);

    // ---- gemm2 tail: h1 row -> wave-local LDS -> MFMA A-frags (rows replicated)
    ((__half2*)hlds[wv])[lane] = __floats2half2_rn(rx, ry);   // wave-local; no barrier
    const int r16 = lane & 15;
    const int kb = (lane >> 4) * 8;
    f32x4 acc[4] = {};
    #pragma unroll
    for (int ks = 0; ks < 4; ks++) {
        half8 af = *(const half8*)(&hlds[wv][ks * 32 + kb]);  // same row in all 16 slots
        #pragma unroll
        for (int nj = 0; nj < 4; nj++) {
            half8 bf = *(const half8*)(Wt2 + (size_t)(nj * 16 + r16) * 128 + ks * 32 + kb);
            acc[nj] = __builtin_amdgcn_mfma_f32_16x16x32_f16(af, bf, acc[nj], 0, 0, 0);
        }
    }
    if (lane < 16) {   // D rows identical; reg 0 = row 0, col = nj*16 + lane
        #pragma unroll
        for (int nj = 0; nj < 4; nj++)
            t2[(size_t)i * 64 + nj * 16 + lane] = (_Float16)(acc[nj][0] * di);
    }
}

// ---------------- layer-2 aggregation fused with pooled accumulation ----------------
// pooled_sums[batch[i]][f] += (sum_{s in N(i) u {i}} t2[s][f]) * dinv[i]
__global__ __launch_bounds__(256) void aggregate_pool(const __half* __restrict__ t,
                                                      const float* __restrict__ dinv,
                                                      const int2* __restrict__ nodeinfo,
                                                      const int* __restrict__ csr_src,
                                                      const int* __restrict__ batch,
                                                      float* __restrict__ pooled_sums, int n) {
    constexpr int F = 64;
    const int wv = threadIdx.x >> 6;
    const int lane = threadIdx.x & 63;
    const int i = blockIdx.x * 4 + wv;
    if (i >= n) return;
    const float di = dinv[i];
    const int2 ni = nodeinfo[i];
    const int e0 = ni.x, e1 = ni.x + ni.y;

    float a0, a1 = 0.f, a2 = 0.f, a3 = 0.f;
    a0 = __half2float(t[(size_t)i * F + lane]);  // self (t2 prescaled by dinv)
    int e = e0;
    for (; e + 8 <= e1; e += 8) {
        int s0 = csr_src[e + 0], s1 = csr_src[e + 1], s2 = csr_src[e + 2], s3 = csr_src[e + 3];
        int s4 = csr_src[e + 4], s5 = csr_src[e + 5], s6 = csr_src[e + 6], s7 = csr_src[e + 7];
        float v0 = __half2float(t[(size_t)s0 * F + lane]);
        float v1 = __half2float(t[(size_t)s1 * F + lane]);
        float v2 = __half2float(t[(size_t)s2 * F + lane]);
        float v3 = __half2float(t[(size_t)s3 * F + lane]);
        float v4 = __half2float(t[(size_t)s4 * F + lane]);
        float v5 = __half2float(t[(size_t)s5 * F + lane]);
        float v6 = __half2float(t[(size_t)s6 * F + lane]);
        float v7 = __half2float(t[(size_t)s7 * F + lane]);
        a0 += v0 + v4; a1 += v1 + v5; a2 += v2 + v6; a3 += v3 + v7;
    }
    for (; e + 4 <= e1; e += 4) {
        int s0 = csr_src[e + 0], s1 = csr_src[e + 1], s2 = csr_src[e + 2], s3 = csr_src[e + 3];
        a0 += __half2float(t[(size_t)s0 * F + lane]);
        a1 += __half2float(t[(size_t)s1 * F + lane]);
        a2 += __half2float(t[(size_t)s2 * F + lane]);
        a3 += __half2float(t[(size_t)s3 * F + lane]);
    }
    for (; e < e1; e++) {
        a0 += __half2float(t[(size_t)csr_src[e] * F + lane]);
    }
    float r = (a0 + a1 + a2 + a3) * di;
    const int g = batch[i];
    atomicAdd(&pooled_sums[(size_t)g * F + lane], r);
}

// ---------------- classifier: /cnt + b2, then @Wl + bl ----------------
__global__ __launch_bounds__(64) void classify(const float* __restrict__ pooled_sums,
                                               const int* __restrict__ batch, int n,
                                               const float* __restrict__ b2,
                                               const float* __restrict__ Wl,
                                               const float* __restrict__ bl,
                                               float* __restrict__ out) {
    __shared__ float pr[64];
    const int g = blockIdx.x;
    const int lane = threadIdx.x;
    int lo = 0, hi = n;
    while (lo < hi) { int mid = (lo + hi) >> 1; if (batch[mid] < g) lo = mid + 1; else hi = mid; }
    const int start = lo;
    hi = n;
    while (lo < hi) { int mid = (lo + hi) >> 1; if (batch[mid] < g + 1) lo = mid + 1; else hi = mid; }
    const float cnt = (float)(lo - start);
    float p = pooled_sums[(size_t)g * 64 + lane] / fmaxf(cnt, 1.0f) + b2[lane];
    pr[lane] = p;
    __syncthreads();
    float acc = bl[lane];
    #pragma unroll 8
    for (int k = 0; k < 64; k++) acc += pr[k] * Wl[k * 64 + lane];
    out[(size_t)g * 64 + lane] = acc;
}

// ---------------- launch ----------------

extern "C" void kernel_launch(void* const* d_in, const int* in_sizes, int n_in,
                              void* d_out, int out_size, void* d_ws, size_t ws_size,
                              hipStream_t stream) {
    const float* x    = (const float*)d_in[0];
    const int*   eidx = (const int*)d_in[1];
    const int*   batch= (const int*)d_in[2];
    const float* W1   = (const float*)d_in[3];
    const float* b1   = (const float*)d_in[4];
    const float* W2   = (const float*)d_in[5];
    const float* b2   = (const float*)d_in[6];
    const float* Wl   = (const float*)d_in[7];
    const float* bl   = (const float*)d_in[8];
    float* out = (float*)d_out;

    const int n_nodes  = in_sizes[0] / FEAT1;     // 50000
    const int n_edges  = in_sizes[1] / 2;         // 800000
    const int n_graphs = out_size / FEAT2;        // 512
    const int* esrc = eidx;
    const int* edst = eidx + n_edges;
    const int nb = (n_nodes + 255) >> 8;          // 196 buckets
    const int npool = n_graphs * FEAT2;           // 32768

    // workspace layout
    char* ws = (char*)d_ws;
    size_t off = 0;
    auto alloc = [&](size_t bytes) -> void* {
        void* p = ws + off;
        off += (bytes + 255) & ~(size_t)255;
        return p;
    };
    _Float16* t1     = (_Float16*)alloc((size_t)n_nodes * FEAT1 * 2); // fp16 (x@W1)*dinv
    _Float16* t2     = (_Float16*)alloc((size_t)n_nodes * FEAT2 * 2); // fp16 (h1@W2)*dinv
    float*    dinv   = (float*)alloc((size_t)n_nodes * 4);
    int2*   nodeinfo = (int2*)alloc((size_t)n_nodes * 8);
    int*    bcur     = (int*)alloc((size_t)nb * 4);
    float*  pooled   = (float*)alloc((size_t)npool * 4);
    _Float16* Wt1    = (_Float16*)alloc(128 * 128 * 2);
    _Float16* Wt2    = (_Float16*)alloc(64 * 128 * 2);
    int*    ebin     = (int*)alloc((size_t)nb * BCAP * 4);
    int*    csr      = (int*)alloc((size_t)nb * BCAP * 4);

    const int nrb = (n_nodes + 127) / 128;        // 391 gemm row-tiles

    // 1. prep: zero bcur+pooled, transpose W1/W2 to fp16
    prep<<<(nb + npool + 255) / 256, 256, 0, stream>>>(W1, W2, Wt1, Wt2, bcur, pooled, nb, npool);
    // 2-3. bucketed CSR build
    bin_scatter<<<(n_edges + 8191) / 8192, 256, 0, stream>>>(esrc, edst, n_edges, nb, bcur, ebin);
    bucket_csr<<<nb, 256, 0, stream>>>(ebin, bcur, n_nodes, csr, nodeinfo, dinv);
    // 4. gemm1: t1 = fp16((x @ W1) * dinv)
    gemm_direct<<<nrb, 256, 0, stream>>>(x, Wt1, dinv, t1, n_nodes);
    // 5. fused agg1 + gemm2 tail -> t2 (prescaled)
    agg1_gemm2<<<(n_nodes + 3) / 4, 256, 0, stream>>>(
        (const __half*)t1, dinv, nodeinfo, csr, b1, Wt2, t2, n_nodes);
    // 6. agg2 + pooled accumulation
    aggregate_pool<<<(n_nodes + 3) / 4, 256, 0, stream>>>(
        (const __half*)t2, dinv, nodeinfo, csr, batch, pooled, n_nodes);
    // 7. classifier
    classify<<<n_graphs, 64, 0, stream>>>(pooled, batch, n_nodes, b2, Wl, bl, out);
}

// Round 13
// 151.374 us; speedup vs baseline: 1.3874x; 1.3874x over previous
//
#include <hip/hip_runtime.h>
#include <hip/hip_fp16.h>
#include <math.h>

// GCN forward: h1 = relu(norm_agg(x@W1)+b1); h2 = norm_agg(h1@W2)+b2;
// g = mean_pool(h2, batch); out = g@Wl + bl.
// norm_agg = D^-1/2 (A+I) D^-1/2, CSR-by-dst pull.
// R3: GEMM writes t_scaled[i] = (in@W)[i]*dinv[i] as FP16.
// R4: CSR via 2-pass bucketed counting sort (one block owns each csr line).
// R8: row-major fp16 gather, edge loop unrolled x8 (latency-bound gather).
// R9: agg2 accumulates pooled sums via global f32 atomics; classify kernel.
// R10: LDS-free MFMA GEMM — A/B fragments loaded DIRECTLY from global
//      (fragment = 8 contiguous k-elems/lane). W pre-transposed to fp16
//      Wt[col][k] by the prep kernel (also zeros bcur+pooled).
// R13: FINAL — revert of R11/R12 fusion experiments (both regressed: a
//      serialized MFMA+LDS tail in the short latency-bound gather loop
//      collapsed effective gather BW 3.6->0.8 TB/s). This is the best
//      measured pipeline: 151.5 us.

#define FEAT1 128
#define FEAT2 64
#define BCAP 8192   // edge capacity per bucket; avg load = 4096

using half8 = __attribute__((ext_vector_type(8))) _Float16;
using f32x4 = __attribute__((ext_vector_type(4))) float;

// ---------------- prep: zero bcur+pooled, transpose W1/W2 to fp16 ----------------
__global__ __launch_bounds__(256) void prep(const float* __restrict__ W1,
                                            const float* __restrict__ W2,
                                            _Float16* __restrict__ Wt1,
                                            _Float16* __restrict__ Wt2,
                                            int* __restrict__ bcur,
                                            float* __restrict__ pooled,
                                            int nb, int npool) {
    const int i = blockIdx.x * 256 + threadIdx.x;
    if (i < nb) bcur[i] = 0;
    const int j = i - nb;
    if (j >= 0 && j < npool) pooled[j] = 0.0f;
    if (i < 128 * 128) {                       // Wt1[c][k] = W1[k][c]
        int k = i & 127, c = i >> 7;
        Wt1[c * 128 + k] = (_Float16)W1[k * 128 + c];
    }
    if (i < 64 * 128) {                        // Wt2[c][k] = W2[k][c]
        int k = i & 127, c = i >> 7;
        Wt2[c * 128 + k] = (_Float16)W2[k * 64 + c];
    }
}

// ---------------- bucketed CSR build ----------------

// pass 1: scatter edges into per-bucket regions, packed src | ((dst&255)<<18)
__global__ __launch_bounds__(256) void bin_scatter(const int* __restrict__ esrc,
                                                   const int* __restrict__ edst,
                                                   int ne, int nb,
                                                   int* __restrict__ bucket_cursor,
                                                   int* __restrict__ ebin) {
    __shared__ int lcnt[256];
    __shared__ int lcur[256];
    const int tid = threadIdx.x;
    const int e0 = blockIdx.x * 8192;
    int dcache[32];                     // edst cached in regs across phases
    lcnt[tid] = 0;
    __syncthreads();
    #pragma unroll
    for (int k = 0; k < 32; k++) {
        int e = e0 + k * 256 + tid;
        dcache[k] = (e < ne) ? edst[e] : -1;
        if (dcache[k] >= 0) atomicAdd(&lcnt[dcache[k] >> 8], 1);
    }
    __syncthreads();
    if (tid < nb && lcnt[tid] > 0)
        lcur[tid] = atomicAdd(&bucket_cursor[tid], lcnt[tid]);
    __syncthreads();
    #pragma unroll
    for (int k = 0; k < 32; k++) {
        int d = dcache[k];
        if (d >= 0) {
            int e = e0 + k * 256 + tid;
            int b = d >> 8;
            int p = atomicAdd(&lcur[b], 1);          // relative position
            if (p < BCAP)                            // capacity guard
                ebin[b * BCAP + p] = esrc[e] | ((d & 255) << 18); // src < 2^17
        }
    }
}

// pass 2: one block per bucket: LDS counts -> scan -> nodeinfo+dinv -> ticket fill
__global__ __launch_bounds__(256) void bucket_csr(const int* __restrict__ ebin,
                                                  const int* __restrict__ bucket_cursor,
                                                  int n_nodes,
                                                  int* __restrict__ csr,
                                                  int2* __restrict__ nodeinfo,
                                                  float* __restrict__ dinv) {
    __shared__ int lcnt[256];
    __shared__ int lscan[256];
    __shared__ int lcur[256];
    const int b = blockIdx.x;
    const int tid = threadIdx.x;
    const int ebeg = b * BCAP;
    int cnt_b = bucket_cursor[b];
    if (cnt_b > BCAP) cnt_b = BCAP;
    const int eend = ebeg + cnt_b;
    lcnt[tid] = 0;
    __syncthreads();
    for (int e = ebeg + tid; e < eend; e += 256)
        atomicAdd(&lcnt[(ebin[e] >> 18) & 255], 1);
    __syncthreads();
    int v = lcnt[tid];
    lscan[tid] = v;
    __syncthreads();
    for (int off = 1; off < 256; off <<= 1) {
        int u = (tid >= off) ? lscan[tid - off] : 0;
        __syncthreads();
        lscan[tid] += u;
        __syncthreads();
    }
    const int start = ebeg + (lscan[tid] - v);   // exclusive scan position
    const int node = (b << 8) + tid;
    if (node < n_nodes) {
        nodeinfo[node] = make_int2(start, v);
        dinv[node] = (float)(1.0 / sqrt((double)(v + 1)));  // +1 self loop
    }
    lcur[tid] = start;
    __syncthreads();
    for (int e = ebeg + tid; e < eend; e += 256) {
        int pk = ebin[e];
        int p = atomicAdd(&lcur[(pk >> 18) & 255], 1);
        csr[p] = pk & 0x3FFFF;
    }
}

// ---------------- LDS-free direct-fragment MFMA GEMM ----------------
// t_out[row, c] = fp16( (A[row,:128] @ W[:128,c]) * dinv[row] )
// 256 thr = 4 waves; each wave owns 32 rows. A-fragments (8 contiguous k/lane)
// loaded once into regs; col-tiles looped reusing them. B-fragments are half8
// loads from Wt[col][k] (fp16, 16-32 KB, L1-resident). No LDS, no barriers.
template <int FOUT, bool A_F16>
__global__ __launch_bounds__(256) void gemm_direct(const void* __restrict__ Aptr,
                                                   const _Float16* __restrict__ Wt,
                                                   const float* __restrict__ dinv,
                                                   _Float16* __restrict__ out, int n) {
    const int wv = threadIdx.x >> 6;
    const int lane = threadIdx.x & 63;
    const int row0 = blockIdx.x * 128 + wv * 32;   // this wave's 32 rows
    const int r16 = lane & 15;
    const int kb = (lane >> 4) * 8;                // k-offset within 32-k step

    // A fragments: [mi][ks], row = row0 + mi*16 + r16, k = ks*32 + kb .. +7
    half8 afrag[2][4];
    #pragma unroll
    for (int mi = 0; mi < 2; mi++) {
        const int grow = row0 + mi * 16 + r16;
        #pragma unroll
        for (int ks = 0; ks < 4; ks++) {
            if constexpr (A_F16) {
                half8 v = {};
                if (grow < n)
                    v = *(const half8*)((const _Float16*)Aptr + (size_t)grow * 128 + ks * 32 + kb);
                afrag[mi][ks] = v;
            } else {
                float4 v0 = {0.f, 0.f, 0.f, 0.f}, v1 = {0.f, 0.f, 0.f, 0.f};
                if (grow < n) {
                    const float* p = (const float*)Aptr + (size_t)grow * 128 + ks * 32 + kb;
                    v0 = *(const float4*)(p);
                    v1 = *(const float4*)(p + 4);
                }
                afrag[mi][ks] = half8{(_Float16)v0.x, (_Float16)v0.y, (_Float16)v0.z, (_Float16)v0.w,
                                      (_Float16)v1.x, (_Float16)v1.y, (_Float16)v1.z, (_Float16)v1.w};
            }
        }
    }

    #pragma unroll
    for (int ct = 0; ct < FOUT / 64; ct++) {
        const int col0 = ct * 64;
        f32x4 acc[2][4] = {};
        #pragma unroll
        for (int ks = 0; ks < 4; ks++) {
            #pragma unroll
            for (int nj = 0; nj < 4; nj++) {
                half8 b = *(const half8*)(Wt + (size_t)(col0 + nj * 16 + r16) * 128 + ks * 32 + kb);
                acc[0][nj] = __builtin_amdgcn_mfma_f32_16x16x32_f16(afrag[0][ks], b, acc[0][nj], 0, 0, 0);
                acc[1][nj] = __builtin_amdgcn_mfma_f32_16x16x32_f16(afrag[1][ks], b, acc[1][nj], 0, 0, 0);
            }
        }
        // C/D layout: col = lane&15, row = (lane>>4)*4 + reg
        #pragma unroll
        for (int mi = 0; mi < 2; mi++) {
            const int gr0 = row0 + mi * 16 + (lane >> 4) * 4;
            #pragma unroll
            for (int r = 0; r < 4; r++) {
                const int grow = gr0 + r;
                if (grow < n) {
                    const float s = dinv[grow];
                    #pragma unroll
                    for (int nj = 0; nj < 4; nj++) {
                        out[(size_t)grow * FOUT + col0 + nj * 16 + r16] =
                            (_Float16)(acc[mi][nj][r] * s);
                    }
                }
            }
        }
    }
}

// ---------------- layer-1 aggregation: fp16 row-sum gather, 8-deep ----------------
// h1[i] = fp16( relu( (sum_{s in N(i) u {i}} t1[s]) * dinv[i] + b1 ) )
__global__ __launch_bounds__(256) void aggregate_l1(const __half* __restrict__ t,
                                                    const float* __restrict__ dinv,
                                                    const int2* __restrict__ nodeinfo,
                                                    const int* __restrict__ csr_src,
                                                    const float* __restrict__ bias,
                                                    __half* __restrict__ outp, int n) {
    constexpr int F = 128;
    const int wv = threadIdx.x >> 6;
    const int lane = threadIdx.x & 63;
    const int i = blockIdx.x * 4 + wv;
    if (i >= n) return;
    const float di = dinv[i];
    const int2 ni = nodeinfo[i];
    const int e0 = ni.x, e1 = ni.x + ni.y;

    float2 a0, a1 = {0.f, 0.f}, a2 = {0.f, 0.f}, a3 = {0.f, 0.f};
    a0 = __half22float2(((const __half2*)(t + (size_t)i * F))[lane]);  // self
    int e = e0;
    for (; e + 8 <= e1; e += 8) {     // 8 row-gathers in flight
        int s0 = csr_src[e + 0], s1 = csr_src[e + 1], s2 = csr_src[e + 2], s3 = csr_src[e + 3];
        int s4 = csr_src[e + 4], s5 = csr_src[e + 5], s6 = csr_src[e + 6], s7 = csr_src[e + 7];
        float2 v0 = __half22float2(((const __half2*)(t + (size_t)s0 * F))[lane]);
        float2 v1 = __half22float2(((const __half2*)(t + (size_t)s1 * F))[lane]);
        float2 v2 = __half22float2(((const __half2*)(t + (size_t)s2 * F))[lane]);
        float2 v3 = __half22float2(((const __half2*)(t + (size_t)s3 * F))[lane]);
        float2 v4 = __half22float2(((const __half2*)(t + (size_t)s4 * F))[lane]);
        float2 v5 = __half22float2(((const __half2*)(t + (size_t)s5 * F))[lane]);
        float2 v6 = __half22float2(((const __half2*)(t + (size_t)s6 * F))[lane]);
        float2 v7 = __half22float2(((const __half2*)(t + (size_t)s7 * F))[lane]);
        a0.x += v0.x + v4.x; a0.y += v0.y + v4.y;
        a1.x += v1.x + v5.x; a1.y += v1.y + v5.y;
        a2.x += v2.x + v6.x; a2.y += v2.y + v6.y;
        a3.x += v3.x + v7.x; a3.y += v3.y + v7.y;
    }
    for (; e + 4 <= e1; e += 4) {
        int s0 = csr_src[e + 0], s1 = csr_src[e + 1], s2 = csr_src[e + 2], s3 = csr_src[e + 3];
        float2 v0 = __half22float2(((const __half2*)(t + (size_t)s0 * F))[lane]);
        float2 v1 = __half22float2(((const __half2*)(t + (size_t)s1 * F))[lane]);
        float2 v2 = __half22float2(((const __half2*)(t + (size_t)s2 * F))[lane]);
        float2 v3 = __half22float2(((const __half2*)(t + (size_t)s3 * F))[lane]);
        a0.x += v0.x; a0.y += v0.y;
        a1.x += v1.x; a1.y += v1.y;
        a2.x += v2.x; a2.y += v2.y;
        a3.x += v3.x; a3.y += v3.y;
    }
    for (; e < e1; e++) {
        int s = csr_src[e];
        float2 v = __half22float2(((const __half2*)(t + (size_t)s * F))[lane]);
        a0.x += v.x; a0.y += v.y;
    }
    float2 b = ((const float2*)bias)[lane];
    float rx = (a0.x + a1.x + a2.x + a3.x) * di + b.x;
    float ry = (a0.y + a1.y + a2.y + a3.y) * di + b.y;
    rx = fmaxf(rx, 0.f); ry = fmaxf(ry, 0.f);
    ((__half2*)(outp + (size_t)i * F))[lane] = __floats2half2_rn(rx, ry);
}

// ---------------- layer-2 aggregation fused with pooled accumulation ----------------
// pooled_sums[batch[i]][f] += (sum_{s in N(i) u {i}} t2[s][f]) * dinv[i]
__global__ __launch_bounds__(256) void aggregate_pool(const __half* __restrict__ t,
                                                      const float* __restrict__ dinv,
                                                      const int2* __restrict__ nodeinfo,
                                                      const int* __restrict__ csr_src,
                                                      const int* __restrict__ batch,
                                                      float* __restrict__ pooled_sums, int n) {
    constexpr int F = 64;
    const int wv = threadIdx.x >> 6;
    const int lane = threadIdx.x & 63;
    const int i = blockIdx.x * 4 + wv;
    if (i >= n) return;
    const float di = dinv[i];
    const int2 ni = nodeinfo[i];
    const int e0 = ni.x, e1 = ni.x + ni.y;

    float a0, a1 = 0.f, a2 = 0.f, a3 = 0.f;
    a0 = __half2float(t[(size_t)i * F + lane]);  // self
    int e = e0;
    for (; e + 8 <= e1; e += 8) {     // 8 row-gathers in flight
        int s0 = csr_src[e + 0], s1 = csr_src[e + 1], s2 = csr_src[e + 2], s3 = csr_src[e + 3];
        int s4 = csr_src[e + 4], s5 = csr_src[e + 5], s6 = csr_src[e + 6], s7 = csr_src[e + 7];
        float v0 = __half2float(t[(size_t)s0 * F + lane]);
        float v1 = __half2float(t[(size_t)s1 * F + lane]);
        float v2 = __half2float(t[(size_t)s2 * F + lane]);
        float v3 = __half2float(t[(size_t)s3 * F + lane]);
        float v4 = __half2float(t[(size_t)s4 * F + lane]);
        float v5 = __half2float(t[(size_t)s5 * F + lane]);
        float v6 = __half2float(t[(size_t)s6 * F + lane]);
        float v7 = __half2float(t[(size_t)s7 * F + lane]);
        a0 += v0 + v4; a1 += v1 + v5; a2 += v2 + v6; a3 += v3 + v7;
    }
    for (; e + 4 <= e1; e += 4) {
        int s0 = csr_src[e + 0], s1 = csr_src[e + 1], s2 = csr_src[e + 2], s3 = csr_src[e + 3];
        a0 += __half2float(t[(size_t)s0 * F + lane]);
        a1 += __half2float(t[(size_t)s1 * F + lane]);
        a2 += __half2float(t[(size_t)s2 * F + lane]);
        a3 += __half2float(t[(size_t)s3 * F + lane]);
    }
    for (; e < e1; e++) {
        a0 += __half2float(t[(size_t)csr_src[e] * F + lane]);
    }
    float r = (a0 + a1 + a2 + a3) * di;
    const int g = batch[i];
    atomicAdd(&pooled_sums[(size_t)g * F + lane], r);
}

// ---------------- classifier: /cnt + b2, then @Wl + bl ----------------
__global__ __launch_bounds__(64) void classify(const float* __restrict__ pooled_sums,
                                               const int* __restrict__ batch, int n,
                                               const float* __restrict__ b2,
                                               const float* __restrict__ Wl,
                                               const float* __restrict__ bl,
                                               float* __restrict__ out) {
    __shared__ float pr[64];
    const int g = blockIdx.x;
    const int lane = threadIdx.x;
    int lo = 0, hi = n;
    while (lo < hi) { int mid = (lo + hi) >> 1; if (batch[mid] < g) lo = mid + 1; else hi = mid; }
    const int start = lo;
    hi = n;
    while (lo < hi) { int mid = (lo + hi) >> 1; if (batch[mid] < g + 1) lo = mid + 1; else hi = mid; }
    const float cnt = (float)(lo - start);
    float p = pooled_sums[(size_t)g * 64 + lane] / fmaxf(cnt, 1.0f) + b2[lane];
    pr[lane] = p;
    __syncthreads();
    float acc = bl[lane];
    #pragma unroll 8
    for (int k = 0; k < 64; k++) acc += pr[k] * Wl[k * 64 + lane];
    out[(size_t)g * 64 + lane] = acc;
}

// ---------------- launch ----------------

extern "C" void kernel_launch(void* const* d_in, const int* in_sizes, int n_in,
                              void* d_out, int out_size, void* d_ws, size_t ws_size,
                              hipStream_t stream) {
    const float* x    = (const float*)d_in[0];
    const int*   eidx = (const int*)d_in[1];
    const int*   batch= (const int*)d_in[2];
    const float* W1   = (const float*)d_in[3];
    const float* b1   = (const float*)d_in[4];
    const float* W2   = (const float*)d_in[5];
    const float* b2   = (const float*)d_in[6];
    const float* Wl   = (const float*)d_in[7];
    const float* bl   = (const float*)d_in[8];
    float* out = (float*)d_out;

    const int n_nodes  = in_sizes[0] / FEAT1;     // 50000
    const int n_edges  = in_sizes[1] / 2;         // 800000
    const int n_graphs = out_size / FEAT2;        // 512
    const int* esrc = eidx;
    const int* edst = eidx + n_edges;
    const int nb = (n_nodes + 255) >> 8;          // 196 buckets
    const int npool = n_graphs * FEAT2;           // 32768

    // workspace layout
    char* ws = (char*)d_ws;
    size_t off = 0;
    auto alloc = [&](size_t bytes) -> void* {
        void* p = ws + off;
        off += (bytes + 255) & ~(size_t)255;
        return p;
    };
    _Float16* t1     = (_Float16*)alloc((size_t)n_nodes * FEAT1 * 2); // fp16 scaled table (reused as t2)
    __half*   h1h    = (__half*)alloc((size_t)n_nodes * FEAT1 * 2);   // fp16 h1 (agg1 out, gemm2 in)
    float*    dinv   = (float*)alloc((size_t)n_nodes * 4);
    int2*   nodeinfo = (int2*)alloc((size_t)n_nodes * 8);
    int*    bcur     = (int*)alloc((size_t)nb * 4);
    float*  pooled   = (float*)alloc((size_t)npool * 4);
    _Float16* Wt1    = (_Float16*)alloc(128 * 128 * 2);
    _Float16* Wt2    = (_Float16*)alloc(64 * 128 * 2);
    int*    ebin     = (int*)alloc((size_t)nb * BCAP * 4);
    int*    csr      = (int*)alloc((size_t)nb * BCAP * 4);

    const int nrb = (n_nodes + 127) / 128;        // 391 row-tiles

    // 1. prep (zero bcur+pooled, transpose W1/W2 to fp16); bucketed CSR build
    prep<<<(nb + npool + 255) / 256, 256, 0, stream>>>(W1, W2, Wt1, Wt2, bcur, pooled, nb, npool);
    bin_scatter<<<(n_edges + 8191) / 8192, 256, 0, stream>>>(esrc, edst, n_edges, nb, bcur, ebin);
    bucket_csr<<<nb, 256, 0, stream>>>(ebin, bcur, n_nodes, csr, nodeinfo, dinv);

    // 2. layer 1: t1 = fp16((x @ W1) * dinv) ; h1 = fp16(relu(agg(t1)*dinv + b1))
    gemm_direct<FEAT1, false><<<nrb, 256, 0, stream>>>(x, Wt1, dinv, t1, n_nodes);
    aggregate_l1<<<(n_nodes + 3) / 4, 256, 0, stream>>>(
        (const __half*)t1, dinv, nodeinfo, csr, b1, h1h, n_nodes);

    // 3. layer 2: t2 = fp16((h1 @ W2) * dinv) ; pooled_sums += agg(t2)*dinv per graph
    gemm_direct<FEAT2, true><<<nrb, 256, 0, stream>>>(h1h, Wt2, dinv, t1, n_nodes);
    aggregate_pool<<<(n_nodes + 3) / 4, 256, 0, stream>>>(
        (const __half*)t1, dinv, nodeinfo, csr, batch, pooled, n_nodes);

    // 4. classifier: /cnt + b2, @Wl + bl
    classify<<<n_graphs, 64, 0, stream>>>(pooled, batch, n_nodes, b2, Wl, bl, out);
}